// Round 4
// baseline (233.608 us; speedup 1.0000x reference)
//
#include <hip/hip_runtime.h>
#include <stdint.h>

#define NB 8
#define NPRED 25200
#define NTOP 1000
#define NCLS 80
#define CONF_T 0.25f
#define IOU_THR 0.45f
#define MAXWH 4096.0f
#define CAP 2048
#define NBINS 1025
#define SBLK 128
#define SBPB 197   // ceil(25200/128): 197*128 = 25216
#define CCAP 64    // per-class candidate cap (fast path); exact fallback if exceeded

typedef unsigned long long u64;
typedef unsigned short u16;

__device__ __forceinline__ u64 shfl_xor_u64(u64 v, int m) {
    int lo = __shfl_xor((int)(unsigned)v, m);
    int hi = __shfl_xor((int)(unsigned)(v >> 32), m);
    return ((u64)(unsigned)hi << 32) | (unsigned)lo;
}

// ---------------------------------------------------------------------------
// K1: score/class per pred. 256 threads / 128 preds: thread pair (t>>1, t&1)
// splits the 80-class argmax 40/40, combined with one __shfl_xor.
// Staging via global_load_lds width=16 (no VGPR round trip).
// ---------------------------------------------------------------------------
__global__ __launch_bounds__(256) void k_score(const float* __restrict__ x,
                                               float* __restrict__ msc,
                                               int* __restrict__ cls) {
#pragma clang fp contract(off)
    __shared__ __align__(16) float sm[SBLK * 85];
    const int b = blockIdx.x / SBPB;
    const int blk = blockIdx.x % SBPB;
    const int t = threadIdx.x;
    const int wave = t >> 6, lane = t & 63;
    const long long TOT4 = (long long)NB * NPRED * 85 / 4;  // 4,284,000
    const long long base4 = ((long long)b * NPRED + (long long)blk * SBLK) * 85 / 4;
    const float4* x4 = (const float4*)x;
    const int tile4 = SBLK * 85 / 4;  // 2720

    for (int k = 0; k < 11; ++k) {
        int ib = k * 256 + wave * 64;      // wave-uniform lds base (float4 units)
        int fi = ib + lane;
        if (fi < tile4) {
            long long gi = base4 + fi;
            if (gi >= TOT4) gi = TOT4 - 1;  // tail clamp (outputs guarded below)
            __builtin_amdgcn_global_load_lds(
                (const __attribute__((address_space(1))) void*)(x4 + gi),
                (__attribute__((address_space(3))) void*)(sm + (size_t)ib * 4),
                16, 0, 0);
        }
    }
    __syncthreads();

    const int p = t >> 1;        // pred within block [0,128)
    const int h = t & 1;         // class-half: 0 -> classes 0..39, 1 -> 40..79
    const int pred = blk * SBLK + p;
    const float* rowp = &sm[p * 85];
    float obj = rowp[4];
    const int cb = 5 + h * 40;
    float best = rowp[cb];
    int bid = h * 40;
    for (int c = 1; c < 40; ++c) {
        float v = rowp[cb + c];
        if (v > best) { best = v; bid = h * 40 + c; }  // strict >: first occurrence
    }
    float obest = __shfl_xor(best, 1);
    int obid = __shfl_xor(bid, 1);
    if (h == 0 && pred < NPRED) {
        float fb = best; int fc = bid;
        if (obest > fb) { fb = obest; fc = obid; }  // ties -> lower class idx (h=0)
        float score = obj * fb;
        int q = b * NPRED + pred;
        msc[q] = (score > CONF_T) ? score : -1.0f;
        cls[q] = fc;
    }
}

// ---------------------------------------------------------------------------
// K2 (fully fused tail): histogram + boundary-bin + compact + bitonic sort +
// gather + PER-CLASS greedy NMS + masked output write. One block per batch.
//
// Why per-class NMS is exact: reference offsets boxes by cls*4096 before the
// full 1000x1000 IoU. Boxes lie in (-0.5, 1.5) per coordinate, so stripes of
// different classes are >4094 apart -> rb-lt <= -4094 -> clipped wh = 0 ->
// inter = 0 -> iou = 0/(sum+1e-9) = 0 < 0.45 EXACTLY (no rounding concern:
// the clip to 0 is exact). Greedy suppression therefore only propagates
// within a class, and within-class processing order = global rank order.
// Same-class IoU here recomputes the OFFSET boxes (o + cls*4096, f32-rounded)
// and applies the identical expression the reference uses -> bit-exact with
// the previous k_iou/k_scan pipeline (absmax 0.0 for 4 rounds).
//
// msc is read ONCE into 25 regs/thread (was 2 global passes).
// keys region (16 KB) is overlaid after gather with {idx[80][64], cnt, sup}.
// ---------------------------------------------------------------------------
__global__ __launch_bounds__(1024) void k_fused(const float* __restrict__ x,
                                                const float* __restrict__ msc,
                                                const int* __restrict__ cls,
                                                float* __restrict__ out) {
#pragma clang fp contract(off)
    __shared__ __align__(16) unsigned char uni[CAP * 8];  // keys | {idx,cnt,sup}
    __shared__ unsigned hh[NBINS];
    __shared__ __align__(16) float4 obx[NTOP];   // un-offset xyxy
    __shared__ float oco[NTOP];                  // cls * 4096
    __shared__ float osc[NTOP];                  // score
    __shared__ int   ocl[NTOP];                  // class id, -1 if invalid
    __shared__ int sB;
    __shared__ unsigned lcnt;
    __shared__ int ovf;
    u64* keys = (u64*)uni;
    const int b = blockIdx.x, t = threadIdx.x;
    const float* ms = msc + (size_t)b * NPRED;

    // single global pass: stash msc in registers (25*1024 = 25600 >= 25200)
    float sv[25];
#pragma unroll
    for (int k = 0; k < 25; ++k) {
        int p = t + k * 1024;
        sv[k] = (p < NPRED) ? ms[p] : -1.0f;
    }

    for (int i = t; i < NBINS; i += 1024) hh[i] = 0;
    if (t == 0) { lcnt = 0; ovf = 0; }
    __syncthreads();

    // pass A: per-batch histogram of score bits (LDS atomics, from regs)
#pragma unroll
    for (int k = 0; k < 25; ++k) {
        float s = sv[k];
        if (s > CONF_T) {
            unsigned bits = __float_as_uint(s);
            int bin = (int)(bits >> 14) - 0xFA00;
            bin = bin < 0 ? 0 : (bin > 1024 ? 1024 : bin);
            atomicAdd(&hh[bin], 1u);
        }
    }
    __syncthreads();

    if (t < 64) {  // wave 0: suffix-count boundary bin B
        const int lane = t;
        const int hi2 = 1024 - 16 * lane;       // lane chunk: bins [hi2-15, hi2]
        unsigned sum = 0;
        for (int k = 0; k < 16; ++k) sum += hh[hi2 - k];
        if (lane == 63) sum += hh[0];
        unsigned v = sum;
        for (int d = 1; d < 64; d <<= 1) {
            unsigned o = __shfl_up(v, d);
            if (lane >= d) v += o;
        }
        unsigned excl = v - sum;                // count strictly above my chunk
        u64 ball = __ballot(v >= NTOP);
        int B = 0;
        if (ball != 0) {
            int sel = __builtin_ctzll(ball);
            if (lane == sel) {
                unsigned run = excl;
                for (int k = 0; k < 16; ++k) {
                    run += hh[hi2 - k];
                    if (run >= NTOP) { B = hi2 - k; break; }
                }
            }
            B = __shfl(B, sel);
        }
        if (lane == 0) sB = B;
    }
    __syncthreads();
    const int B = sB;

    // pass B: compact candidates (bin >= B) into LDS keys (from regs)
#pragma unroll
    for (int k = 0; k < 25; ++k) {
        float s = sv[k];
        if (s > CONF_T) {
            unsigned bits = __float_as_uint(s);
            int bin = (int)(bits >> 14) - 0xFA00;
            bin = bin < 0 ? 0 : (bin > 1024 ? 1024 : bin);
            if (bin >= B) {
                unsigned slot = atomicAdd(&lcnt, 1u);
                if (slot < CAP)
                    keys[slot] = ((u64)(~bits) << 32) | (unsigned)(t + k * 1024);
            }
        }
    }
    __syncthreads();
    unsigned c = lcnt; if (c > CAP) c = CAP;
    for (int i = (int)c + t; i < CAP; i += 1024) keys[i] = ~0ULL;
    __syncthreads();

    // ---- hybrid bitonic sort, CAP=2048 keys ascending ----
    const unsigned ia = (((unsigned)t & ~63u) << 1) | ((unsigned)t & 63u);
    const unsigned ib = ia + 64u;

    auto ce = [&](u64& v, unsigned i, unsigned j, unsigned k) {
        u64 pv = shfl_xor_u64(v, (int)j);
        bool asc = ((i & k) == 0u);
        bool lower = ((i & j) == 0u);
        bool takeMin = (asc == lower);
        bool less = (v < pv);
        v = (takeMin == less) ? v : pv;
    };

    // phase 1: k = 2..64 entirely in registers (partners within 64-segment)
    {
        u64 a = keys[ia], d = keys[ib];
        for (unsigned k = 2; k <= 64; k <<= 1)
            for (unsigned j = k >> 1; j >= 1; j >>= 1) {
                ce(a, ia, j, k);
                ce(d, ib, j, k);
            }
        keys[ia] = a; keys[ib] = d;
    }
    __syncthreads();

    // phase 2: k = 128..2048; j>=64 in LDS, j<=32 in registers
    for (unsigned k = 128; k <= CAP; k <<= 1) {
        for (unsigned j = k >> 1; j >= 64; j >>= 1) {
            unsigned i = (((unsigned)t & ~(j - 1)) << 1) | ((unsigned)t & (j - 1));
            unsigned pi = i | j;
            bool up = ((i & k) == 0);
            u64 a = keys[i], d = keys[pi];
            bool sw = up ? (a > d) : (a < d);
            if (sw) { keys[i] = d; keys[pi] = a; }
            __syncthreads();
        }
        u64 a = keys[ia], d = keys[ib];
        for (unsigned j = 32; j >= 1; j >>= 1) {
            ce(a, ia, j, k);
            ce(d, ib, j, k);
        }
        keys[ia] = a; keys[ib] = d;
        __syncthreads();
    }

    // gather top-1000 into LDS SoA
    if (t < NTOP) {
        u64 key = keys[t];
        unsigned p = (unsigned)key;
        float score = __uint_as_float(~(unsigned)(key >> 32));
        bool v = score > CONF_T;
        float4 o = make_float4(0.f, 0.f, 0.f, 0.f);
        float co = 0.f; int cid = -1;
        if (v) {
            const float* xp = x + ((size_t)b * NPRED + p) * 85;
            float xc = xp[0], yc = xp[1], w = xp[2], h = xp[3];
            float hw = w * 0.5f, hh2 = h * 0.5f;
            o.x = xc - hw; o.y = yc - hh2; o.z = xc + hw; o.w = yc + hh2;
            cid = cls[(size_t)b * NPRED + p];
            co = (float)cid * MAXWH;
        }
        obx[t] = o; oco[t] = co; osc[t] = score; ocl[t] = cid;
    }
    __syncthreads();    // keys dead from here; overlay {idx, cnt, sup}

    u16* idx = (u16*)uni;                      // [80][CCAP]  10240 B
    int* cnt = (int*)(uni + 80 * CCAP * 2);    // 80 ints     (offset 10240)
    unsigned char* sup = uni + 80 * CCAP * 2 + 320;  // 1000 B (offset 10560)

    if (t < NTOP) sup[t] = 0;
    if (t < NCLS) {  // order-preserving per-class index lists (broadcast reads)
        int n = 0;
        for (int r = 0; r < NTOP; ++r)
            if (ocl[r] == t) { if (n < CCAP) idx[t * CCAP + n] = (u16)r; ++n; }
        cnt[t] = n;
        if (n > CCAP) ovf = 1;
    }
    __syncthreads();

    if (ovf == 0) {
        // fast path: per-class greedy, one thread per class
        if (t < NCLS) {
            int n = cnt[t];
            for (int a2 = 0; a2 < n; ++a2) {
                int ra = idx[t * CCAP + a2];
                if (sup[ra]) continue;               // suppressed rows don't suppress
                float4 A = obx[ra]; float cA = oco[ra];
                float ax1 = A.x + cA, ay1 = A.y + cA;
                float ax2 = A.z + cA, ay2 = A.w + cA;
                float areaA = (ax2 - ax1) * (ay2 - ay1);
                for (int d2 = a2 + 1; d2 < n; ++d2) {
                    int rd = idx[t * CCAP + d2];
                    if (sup[rd]) continue;
                    float4 Bb = obx[rd];             // same class -> same offset cA
                    float bx1 = Bb.x + cA, by1 = Bb.y + cA;
                    float bx2 = Bb.z + cA, by2 = Bb.w + cA;
                    float ltx = fmaxf(ax1, bx1), lty = fmaxf(ay1, by1);
                    float rbx = fminf(ax2, bx2), rby = fminf(ay2, by2);
                    float ww = fmaxf(rbx - ltx, 0.0f), hh3 = fmaxf(rby - lty, 0.0f);
                    float inter = ww * hh3;
                    float areaB = (bx2 - bx1) * (by2 - by1);
                    float iou = inter / (((areaA + areaB) - inter) + 1e-9f);
                    if (iou > IOU_THR) sup[rd] = 1;
                }
            }
        }
    } else {
        // exact fallback (probability ~1e-21 with this data): serial greedy
        if (t == 0) {
            for (int a2 = 0; a2 < NTOP; ++a2) {
                if (ocl[a2] < 0 || sup[a2]) continue;
                float4 A = obx[a2]; float cA = oco[a2];
                float ax1 = A.x + cA, ay1 = A.y + cA;
                float ax2 = A.z + cA, ay2 = A.w + cA;
                float areaA = (ax2 - ax1) * (ay2 - ay1);
                for (int d2 = a2 + 1; d2 < NTOP; ++d2) {
                    if (ocl[d2] != ocl[a2] || sup[d2]) continue;
                    float4 Bb = obx[d2];
                    float bx1 = Bb.x + cA, by1 = Bb.y + cA;
                    float bx2 = Bb.z + cA, by2 = Bb.w + cA;
                    float ltx = fmaxf(ax1, bx1), lty = fmaxf(ay1, by1);
                    float rbx = fminf(ax2, bx2), rby = fminf(ay2, by2);
                    float ww = fmaxf(rbx - ltx, 0.0f), hh3 = fmaxf(rby - lty, 0.0f);
                    float inter = ww * hh3;
                    float areaB = (bx2 - bx1) * (by2 - by1);
                    float iou = inter / (((areaA + areaB) - inter) + 1e-9f);
                    if (iou > IOU_THR) sup[d2] = 1;
                }
            }
        }
    }
    __syncthreads();

    // masked output write
    if (t < NTOP) {
        bool keep = (ocl[t] >= 0) && (sup[t] == 0);
        float4 o = obx[t];
        size_t d6 = ((size_t)b * NTOP + t) * 6;
        out[d6 + 0] = keep ? o.x : 0.0f;
        out[d6 + 1] = keep ? o.y : 0.0f;
        out[d6 + 2] = keep ? o.z : 0.0f;
        out[d6 + 3] = keep ? o.w : 0.0f;
        out[d6 + 4] = keep ? osc[t] : 0.0f;
        out[d6 + 5] = keep ? (float)ocl[t] : 0.0f;
    }
}

// ---------------------------------------------------------------------------
extern "C" void kernel_launch(void* const* d_in, const int* in_sizes, int n_in,
                              void* d_out, int out_size, void* d_ws, size_t ws_size,
                              hipStream_t stream) {
    const float* x = (const float*)d_in[0];
    char* ws = (char*)d_ws;
    float* msc = (float*)(ws);                       //      0 .. 806400
    int* cls = (int*)(ws + 806400);                  // 806400 .. 1612800

    k_score<<<NB * SBPB, 256, 0, stream>>>(x, msc, cls);
    k_fused<<<NB, 1024, 0, stream>>>(x, msc, cls, (float*)d_out);
}

// Round 5
// 134.850 us; speedup vs baseline: 1.7324x; 1.7324x over previous
//
#include <hip/hip_runtime.h>
#include <stdint.h>

#define NB 8
#define NPRED 25200
#define NTOP 1000
#define NCLS 80
#define CONF_T 0.25f
#define IOU_THR 0.45f
#define MAXWH 4096.0f
#define CAP 2048
#define NBINS 1025
#define SBLK 128
#define SBPB 197   // ceil(25200/128): 197*128 = 25216

typedef unsigned long long u64;

__device__ __forceinline__ u64 shfl_xor_u64(u64 v, int m) {
    int lo = __shfl_xor((int)(unsigned)v, m);
    int hi = __shfl_xor((int)(unsigned)(v >> 32), m);
    return ((u64)(unsigned)hi << 32) | (unsigned)lo;
}

// ---------------------------------------------------------------------------
// K1: score/class per pred. 256 threads / 128 preds: thread pair (t>>1, t&1)
// splits the 80-class argmax 40/40, combined with one __shfl_xor.
// Staging via global_load_lds width=16 (no VGPR round trip).
// ---------------------------------------------------------------------------
__global__ __launch_bounds__(256) void k_score(const float* __restrict__ x,
                                               float* __restrict__ msc,
                                               int* __restrict__ cls) {
#pragma clang fp contract(off)
    __shared__ __align__(16) float sm[SBLK * 85];
    const int b = blockIdx.x / SBPB;
    const int blk = blockIdx.x % SBPB;
    const int t = threadIdx.x;
    const int wave = t >> 6, lane = t & 63;
    const long long TOT4 = (long long)NB * NPRED * 85 / 4;  // 4,284,000
    const long long base4 = ((long long)b * NPRED + (long long)blk * SBLK) * 85 / 4;
    const float4* x4 = (const float4*)x;
    const int tile4 = SBLK * 85 / 4;  // 2720

    for (int k = 0; k < 11; ++k) {
        int ib = k * 256 + wave * 64;      // wave-uniform lds base (float4 units)
        int fi = ib + lane;
        if (fi < tile4) {
            long long gi = base4 + fi;
            if (gi >= TOT4) gi = TOT4 - 1;  // tail clamp (outputs guarded below)
            __builtin_amdgcn_global_load_lds(
                (const __attribute__((address_space(1))) void*)(x4 + gi),
                (__attribute__((address_space(3))) void*)(sm + (size_t)ib * 4),
                16, 0, 0);
        }
    }
    __syncthreads();

    const int p = t >> 1;        // pred within block [0,128)
    const int h = t & 1;         // class-half: 0 -> classes 0..39, 1 -> 40..79
    const int pred = blk * SBLK + p;
    const float* rowp = &sm[p * 85];
    float obj = rowp[4];
    const int cb = 5 + h * 40;
    float best = rowp[cb];
    int bid = h * 40;
    for (int c = 1; c < 40; ++c) {
        float v = rowp[cb + c];
        if (v > best) { best = v; bid = h * 40 + c; }  // strict >: first occurrence
    }
    float obest = __shfl_xor(best, 1);
    int obid = __shfl_xor(bid, 1);
    if (h == 0 && pred < NPRED) {
        float fb = best; int fc = bid;
        if (obest > fb) { fb = obest; fc = obid; }  // ties -> lower class idx (h=0)
        float score = obj * fb;
        int q = b * NPRED + pred;
        msc[q] = (score > CONF_T) ? score : -1.0f;
        cls[q] = fc;
    }
}

// ---------------------------------------------------------------------------
// K2 (fused tail): histogram + boundary-bin + compact + u64 bitonic sort +
// gather + class-grouping u32 sort + WAVE-PARALLEL per-class ballot greedy +
// masked output write. One block per batch.
//
// Round-4 lesson: the 80-thread serial list build + dependent-LDS-chain
// greedy were ds_read-LATENCY-bound (~120cy single-outstanding, m117) =
// 166 us. This version has NO serial dependent LDS chains:
//  - grouping = u32 bitonic sort of (cls<<10|rank), conflict-free LDS +
//    shfl levels, all 1024 threads;
//  - greedy = one WAVE per class, candidates lane-resident in registers,
//    ballot/ctz loop (~#kept iterations of pure VALU + 1 ballot each).
// Exactness: cross-class IoU is exactly 0 (stripes 4094 apart -> clipped
// wh=0 -> inter=0 -> iou=0<0.45), so suppression is class-local. Same-class
// IoU recomputes OFFSET boxes (o + cls*4096, f32) with the reference's
// exact expression and evaluation order (fmax/fmin/add commutativity ->
// bit-identical); absmax has been 0.0 with this formula for 5 rounds.
// n>64-per-class fast-path overflow -> exact serial fallback (P ~ 1e-40).
// ---------------------------------------------------------------------------
__global__ __launch_bounds__(1024) void k_fused(const float* __restrict__ x,
                                                const float* __restrict__ msc,
                                                const int* __restrict__ cls,
                                                float* __restrict__ out) {
#pragma clang fp contract(off)
    __shared__ __align__(16) unsigned char uni[CAP * 8];  // keys | keys32+seg+sup
    __shared__ unsigned hh[NBINS];
    __shared__ __align__(16) float4 obx[NTOP];   // un-offset xyxy
    __shared__ float oco[NTOP];                  // cls * 4096
    __shared__ float osc[NTOP];                  // score
    __shared__ int   ocl[NTOP];                  // class id, -1 if invalid
    __shared__ int sB;
    __shared__ unsigned lcnt;
    __shared__ int ovf;
    u64* keys = (u64*)uni;
    const int b = blockIdx.x, t = threadIdx.x;
    const float* ms = msc + (size_t)b * NPRED;

    // single global pass: stash msc in registers (25*1024 = 25600 >= 25200)
    float sv[25];
#pragma unroll
    for (int k = 0; k < 25; ++k) {
        int p = t + k * 1024;
        sv[k] = (p < NPRED) ? ms[p] : -1.0f;
    }

    for (int i = t; i < NBINS; i += 1024) hh[i] = 0;
    if (t == 0) { lcnt = 0; ovf = 0; }
    __syncthreads();

    // pass A: per-batch histogram of score bits (LDS atomics, from regs)
#pragma unroll
    for (int k = 0; k < 25; ++k) {
        float s = sv[k];
        if (s > CONF_T) {
            unsigned bits = __float_as_uint(s);
            int bin = (int)(bits >> 14) - 0xFA00;
            bin = bin < 0 ? 0 : (bin > 1024 ? 1024 : bin);
            atomicAdd(&hh[bin], 1u);
        }
    }
    __syncthreads();

    if (t < 64) {  // wave 0: suffix-count boundary bin B
        const int lane = t;
        const int hi2 = 1024 - 16 * lane;       // lane chunk: bins [hi2-15, hi2]
        unsigned sum = 0;
        for (int k = 0; k < 16; ++k) sum += hh[hi2 - k];
        if (lane == 63) sum += hh[0];
        unsigned v = sum;
        for (int d = 1; d < 64; d <<= 1) {
            unsigned o = __shfl_up(v, d);
            if (lane >= d) v += o;
        }
        unsigned excl = v - sum;                // count strictly above my chunk
        u64 ball = __ballot(v >= NTOP);
        int B = 0;
        if (ball != 0) {
            int sel = __builtin_ctzll(ball);
            if (lane == sel) {
                unsigned run = excl;
                for (int k = 0; k < 16; ++k) {
                    run += hh[hi2 - k];
                    if (run >= NTOP) { B = hi2 - k; break; }
                }
            }
            B = __shfl(B, sel);
        }
        if (lane == 0) sB = B;
    }
    __syncthreads();
    const int B = sB;

    // pass B: compact candidates (bin >= B) into LDS keys (from regs)
#pragma unroll
    for (int k = 0; k < 25; ++k) {
        float s = sv[k];
        if (s > CONF_T) {
            unsigned bits = __float_as_uint(s);
            int bin = (int)(bits >> 14) - 0xFA00;
            bin = bin < 0 ? 0 : (bin > 1024 ? 1024 : bin);
            if (bin >= B) {
                unsigned slot = atomicAdd(&lcnt, 1u);
                if (slot < CAP)
                    keys[slot] = ((u64)(~bits) << 32) | (unsigned)(t + k * 1024);
            }
        }
    }
    __syncthreads();
    unsigned c = lcnt; if (c > CAP) c = CAP;
    for (int i = (int)c + t; i < CAP; i += 1024) keys[i] = ~0ULL;
    __syncthreads();

    // ---- hybrid bitonic sort, CAP=2048 u64 keys ascending ----
    const unsigned ia = (((unsigned)t & ~63u) << 1) | ((unsigned)t & 63u);
    const unsigned ib = ia + 64u;

    auto ce = [&](u64& v, unsigned i, unsigned j, unsigned k) {
        u64 pv = shfl_xor_u64(v, (int)j);
        bool asc = ((i & k) == 0u);
        bool lower = ((i & j) == 0u);
        bool takeMin = (asc == lower);
        bool less = (v < pv);
        v = (takeMin == less) ? v : pv;
    };

    {   // phase 1: k = 2..64 entirely in registers
        u64 a = keys[ia], d = keys[ib];
        for (unsigned k = 2; k <= 64; k <<= 1)
            for (unsigned j = k >> 1; j >= 1; j >>= 1) {
                ce(a, ia, j, k);
                ce(d, ib, j, k);
            }
        keys[ia] = a; keys[ib] = d;
    }
    __syncthreads();

    // phase 2: k = 128..2048; j>=64 in LDS, j<=32 in registers
    for (unsigned k = 128; k <= CAP; k <<= 1) {
        for (unsigned j = k >> 1; j >= 64; j >>= 1) {
            unsigned i = (((unsigned)t & ~(j - 1)) << 1) | ((unsigned)t & (j - 1));
            unsigned pi = i | j;
            bool up = ((i & k) == 0);
            u64 a = keys[i], d = keys[pi];
            bool sw = up ? (a > d) : (a < d);
            if (sw) { keys[i] = d; keys[pi] = a; }
            __syncthreads();
        }
        u64 a = keys[ia], d = keys[ib];
        for (unsigned j = 32; j >= 1; j >>= 1) {
            ce(a, ia, j, k);
            ce(d, ib, j, k);
        }
        keys[ia] = a; keys[ib] = d;
        __syncthreads();
    }

    // gather top-1000 into LDS SoA
    if (t < NTOP) {
        u64 key = keys[t];
        unsigned p = (unsigned)key;
        float score = __uint_as_float(~(unsigned)(key >> 32));
        bool v = score > CONF_T;
        float4 o = make_float4(0.f, 0.f, 0.f, 0.f);
        float co = 0.f; int cid = -1;
        if (v) {
            const float* xp = x + ((size_t)b * NPRED + p) * 85;
            float xc = xp[0], yc = xp[1], w = xp[2], h = xp[3];
            float hw = w * 0.5f, hh2 = h * 0.5f;
            o.x = xc - hw; o.y = yc - hh2; o.z = xc + hw; o.w = yc + hh2;
            cid = cls[(size_t)b * NPRED + p];
            co = (float)cid * MAXWH;
        }
        obx[t] = o; oco[t] = co; osc[t] = score; ocl[t] = cid;
    }
    __syncthreads();    // u64 keys dead; overlay keys32/clsStart/clsEnd/sup

    unsigned* keys32 = (unsigned*)uni;              // 1024 u32   (4096 B)
    int* clsStart = (int*)(uni + 4096);             // 80 ints
    int* clsEnd = (int*)(uni + 4416);               // 80 ints
    unsigned char* sup = uni + 4736;                // 1000 B

    // ---- class-grouping sort: key32 = (cls<<10)|rank, 1024 elems, 1 per thread
    unsigned v32 = (t < NTOP && ocl[t] >= 0)
                       ? (((unsigned)ocl[t] << 10) | (unsigned)t) : 0xFFFFFFFFu;

    auto ce32 = [&](unsigned& v, unsigned j, unsigned k) {
        unsigned pv = (unsigned)__shfl_xor((int)v, (int)j);
        bool asc = (((unsigned)t & k) == 0u);
        bool lower = (((unsigned)t & j) == 0u);
        bool takeMin = (asc == lower);
        v = ((v < pv) == takeMin) ? v : pv;
    };

    for (unsigned k = 2; k <= 64; k <<= 1)          // intra-wave levels
        for (unsigned j = k >> 1; j >= 1; j >>= 1) ce32(v32, j, k);

    for (unsigned k = 128; k <= 1024; k <<= 1) {
        for (unsigned j = k >> 1; j >= 64; j >>= 1) {   // LDS levels (stride-1)
            keys32[t] = v32;
            __syncthreads();
            unsigned pv = keys32[t ^ j];
            bool asc = (((unsigned)t & k) == 0u);
            bool lower = (((unsigned)t & j) == 0u);
            bool takeMin = (asc == lower);
            v32 = ((v32 < pv) == takeMin) ? v32 : pv;
            __syncthreads();
        }
        for (unsigned j = 32; j >= 1; j >>= 1) ce32(v32, j, k);
    }
    if (t < NTOP) sup[t] = 0;
    if (t < NCLS) { clsStart[t] = 0; clsEnd[t] = 0; }
    keys32[t] = v32;
    __syncthreads();

    // segment boundaries (valid keys are contiguous at the front)
    {
        unsigned kk = keys32[t];
        if (kk != 0xFFFFFFFFu) {
            int c2 = (int)(kk >> 10);
            unsigned prev = (t > 0) ? keys32[t - 1] : 0xFFFFFFFFu;
            if (t == 0 || (int)(prev >> 10) != c2) clsStart[c2] = t;
            unsigned nxt = (t < 1023) ? keys32[t + 1] : 0xFFFFFFFFu;
            if (t == 1023 || (int)(nxt >> 10) != c2) clsEnd[c2] = t + 1;
        }
    }
    __syncthreads();

    // ---- per-class ballot greedy: one wave per class, 5 rounds ----
    {
        const int waveId = t >> 6, lane2 = t & 63;
        for (int c2 = waveId; c2 < NCLS; c2 += 16) {
            int s2 = clsStart[c2];
            int n2 = clsEnd[c2] - s2;
            if (n2 <= 0) continue;
            if (n2 > 64) { ovf = 1; continue; }
            int rank = 0;
            float ax1v = 0.f, ay1v = 0.f, ax2v = 0.f, ay2v = 0.f, arv = 0.f;
            if (lane2 < n2) {
                rank = (int)(keys32[s2 + lane2] & 1023u);
                float4 A = obx[rank]; float cA = oco[rank];
                ax1v = A.x + cA; ay1v = A.y + cA;
                ax2v = A.z + cA; ay2v = A.w + cA;
                arv = (ax2v - ax1v) * (ay2v - ay1v);
            }
            u64 alive = (n2 >= 64) ? ~0ull : ((1ull << n2) - 1ull);
            u64 kept = 0;
            while (alive) {
                int i = (int)__builtin_ctzll(alive);
                u64 bit = 1ull << i;
                kept |= bit;
                float bx1 = __shfl(ax1v, i), by1 = __shfl(ay1v, i);
                float bx2 = __shfl(ax2v, i), by2 = __shfl(ay2v, i);
                float bar = __shfl(arv, i);
                float ltx = fmaxf(bx1, ax1v), lty = fmaxf(by1, ay1v);
                float rbx = fminf(bx2, ax2v), rby = fminf(by2, ay2v);
                float ww = fmaxf(rbx - ltx, 0.0f), hh3 = fmaxf(rby - lty, 0.0f);
                float inter = ww * hh3;
                float iou = inter / (((bar + arv) - inter) + 1e-9f);
                u64 suppr = __ballot(iou > IOU_THR);
                alive &= ~(suppr | bit);
            }
            if (lane2 < n2) sup[rank] = ((kept >> lane2) & 1ull) ? 0 : 1;
        }
    }
    __syncthreads();

    // exact serial fallback for classes with >64 candidates (P ~ 1e-40)
    if (ovf && t == 0) {
        for (int c2 = 0; c2 < NCLS; ++c2) {
            int s2 = clsStart[c2], e2 = clsEnd[c2];
            if (e2 - s2 <= 64) continue;
            for (int a2 = s2; a2 < e2; ++a2) {
                int ra = (int)(keys32[a2] & 1023u);
                if (sup[ra]) continue;
                float4 A = obx[ra]; float cA = oco[ra];
                float ax1 = A.x + cA, ay1 = A.y + cA;
                float ax2 = A.z + cA, ay2 = A.w + cA;
                float areaA = (ax2 - ax1) * (ay2 - ay1);
                for (int d2 = a2 + 1; d2 < e2; ++d2) {
                    int rd = (int)(keys32[d2] & 1023u);
                    if (sup[rd]) continue;
                    float4 Bb = obx[rd];
                    float bx1 = Bb.x + cA, by1 = Bb.y + cA;
                    float bx2 = Bb.z + cA, by2 = Bb.w + cA;
                    float ltx = fmaxf(ax1, bx1), lty = fmaxf(ay1, by1);
                    float rbx = fminf(ax2, bx2), rby = fminf(ay2, by2);
                    float ww = fmaxf(rbx - ltx, 0.0f), hh3 = fmaxf(rby - lty, 0.0f);
                    float inter = ww * hh3;
                    float areaB = (bx2 - bx1) * (by2 - by1);
                    float iou = inter / (((areaA + areaB) - inter) + 1e-9f);
                    if (iou > IOU_THR) sup[rd] = 1;
                }
            }
        }
    }
    __syncthreads();

    // masked output write
    if (t < NTOP) {
        bool keep = (ocl[t] >= 0) && (sup[t] == 0);
        float4 o = obx[t];
        size_t d6 = ((size_t)b * NTOP + t) * 6;
        out[d6 + 0] = keep ? o.x : 0.0f;
        out[d6 + 1] = keep ? o.y : 0.0f;
        out[d6 + 2] = keep ? o.z : 0.0f;
        out[d6 + 3] = keep ? o.w : 0.0f;
        out[d6 + 4] = keep ? osc[t] : 0.0f;
        out[d6 + 5] = keep ? (float)ocl[t] : 0.0f;
    }
}

// ---------------------------------------------------------------------------
extern "C" void kernel_launch(void* const* d_in, const int* in_sizes, int n_in,
                              void* d_out, int out_size, void* d_ws, size_t ws_size,
                              hipStream_t stream) {
    const float* x = (const float*)d_in[0];
    char* ws = (char*)d_ws;
    float* msc = (float*)(ws);                       //      0 .. 806400
    int* cls = (int*)(ws + 806400);                  // 806400 .. 1612800

    k_score<<<NB * SBPB, 256, 0, stream>>>(x, msc, cls);
    k_fused<<<NB, 1024, 0, stream>>>(x, msc, cls, (float*)d_out);
}

// Round 6
// 133.962 us; speedup vs baseline: 1.7438x; 1.0066x over previous
//
#include <hip/hip_runtime.h>
#include <stdint.h>

#define NB 8
#define NPRED 25200
#define NTOP 1000
#define NCLS 80
#define CONF_T 0.25f
#define IOU_THR 0.45f
#define MAXWH 4096.0f
#define CAP 2048
#define NBINS2 8192   // fine bins: bits>>11 - 0x7D000, clamped to [0, 8191]
#define SBLK 128
#define SBPB 197   // ceil(25200/128): 197*128 = 25216

typedef unsigned long long u64;

__device__ __forceinline__ u64 shfl_xor_u64(u64 v, int m) {
    int lo = __shfl_xor((int)(unsigned)v, m);
    int hi = __shfl_xor((int)(unsigned)(v >> 32), m);
    return ((u64)(unsigned)hi << 32) | (unsigned)lo;
}
__device__ __forceinline__ u64 shfl_u64(u64 v, int src) {
    int lo = __shfl((int)(unsigned)v, src);
    int hi = __shfl((int)(unsigned)(v >> 32), src);
    return ((u64)(unsigned)hi << 32) | (unsigned)lo;
}

// ---------------------------------------------------------------------------
// K1: score/class per pred. 256 threads / 128 preds: thread pair (t>>1, t&1)
// splits the 80-class argmax 40/40, combined with one __shfl_xor.
// Staging via global_load_lds width=16 (no VGPR round trip).
// ---------------------------------------------------------------------------
__global__ __launch_bounds__(256) void k_score(const float* __restrict__ x,
                                               float* __restrict__ msc,
                                               int* __restrict__ cls) {
#pragma clang fp contract(off)
    __shared__ __align__(16) float sm[SBLK * 85];
    const int b = blockIdx.x / SBPB;
    const int blk = blockIdx.x % SBPB;
    const int t = threadIdx.x;
    const int wave = t >> 6, lane = t & 63;
    const long long TOT4 = (long long)NB * NPRED * 85 / 4;  // 4,284,000
    const long long base4 = ((long long)b * NPRED + (long long)blk * SBLK) * 85 / 4;
    const float4* x4 = (const float4*)x;
    const int tile4 = SBLK * 85 / 4;  // 2720

    for (int k = 0; k < 11; ++k) {
        int ib = k * 256 + wave * 64;      // wave-uniform lds base (float4 units)
        int fi = ib + lane;
        if (fi < tile4) {
            long long gi = base4 + fi;
            if (gi >= TOT4) gi = TOT4 - 1;  // tail clamp (outputs guarded below)
            __builtin_amdgcn_global_load_lds(
                (const __attribute__((address_space(1))) void*)(x4 + gi),
                (__attribute__((address_space(3))) void*)(sm + (size_t)ib * 4),
                16, 0, 0);
        }
    }
    __syncthreads();

    const int p = t >> 1;        // pred within block [0,128)
    const int h = t & 1;         // class-half: 0 -> classes 0..39, 1 -> 40..79
    const int pred = blk * SBLK + p;
    const float* rowp = &sm[p * 85];
    float obj = rowp[4];
    const int cb = 5 + h * 40;
    float best = rowp[cb];
    int bid = h * 40;
    for (int c = 1; c < 40; ++c) {
        float v = rowp[cb + c];
        if (v > best) { best = v; bid = h * 40 + c; }  // strict >: first occurrence
    }
    float obest = __shfl_xor(best, 1);
    int obid = __shfl_xor(bid, 1);
    if (h == 0 && pred < NPRED) {
        float fb = best; int fc = bid;
        if (obest > fb) { fb = obest; fc = obid; }  // ties -> lower class idx (h=0)
        float score = obj * fb;
        int q = b * NPRED + pred;
        msc[q] = (score > CONF_T) ? score : -1.0f;
        cls[q] = fc;
    }
}

// ---------------------------------------------------------------------------
// K2 (fused tail). Round-6 changes vs round 5 (which was 47.8 us, ~47%
// VALU-busy on its 8 CUs):
//  - 8192 fine histogram bins (bits>>11): boundary bin holds ~2.3 candidates,
//    so lcnt <= 1024 with P ~ 1-1e-15 -> 1024-element 1-elem/thread bitonic
//    (45 reg levels + 10 conflict-free LDS read-partner rounds) instead of
//    the 2048 2-elem/thread hybrid (~2.2x less sort work). The old 2048 path
//    is kept verbatim as the exact fallback when lcnt > 1024.
//  - class-grouping u32 bitonic REPLACED by per-class rank bitmasks
//    bm[80][16] (LDS atomicOr; bit = global rank). Greedy wave extracts its
//    lane's candidate as the lane-th set bit (shfl popcount scan + 6-step
//    bit select) -> rank order preserved with ~2 barriers instead of ~20
//    and zero compare-exchange work.
// Exactness unchanged: cross-class IoU exactly 0 (stripes 4094 apart ->
// clipped wh=0 -> iou=0<0.45); same-class IoU recomputes OFFSET boxes with
// the reference's expression (fmax/fmin/add/mul symmetric -> bit-identical);
// absmax 0.0 for 6 rounds. Per-class n>64 -> exact serial fallback.
// ---------------------------------------------------------------------------
__global__ __launch_bounds__(1024) void k_fused(const float* __restrict__ x,
                                                const float* __restrict__ msc,
                                                const int* __restrict__ cls,
                                                float* __restrict__ out) {
#pragma clang fp contract(off)
    __shared__ __align__(16) unsigned char uni[CAP * 8];  // keys | ctmp | bm+sup
    __shared__ __align__(16) unsigned hh[NBINS2];
    __shared__ __align__(16) float4 obx[NTOP];   // un-offset xyxy
    __shared__ float oco[NTOP];                  // cls * 4096
    __shared__ float osc[NTOP];                  // score
    __shared__ int   ocl[NTOP];                  // class id, -1 if invalid
    __shared__ int sB;
    __shared__ unsigned lcnt;
    __shared__ int ovf;
    u64* keys = (u64*)uni;
    const int b = blockIdx.x, t = threadIdx.x;
    const float* ms = msc + (size_t)b * NPRED;

    // single global pass: stash msc in registers (25*1024 = 25600 >= 25200)
    float sv[25];
#pragma unroll
    for (int k = 0; k < 25; ++k) {
        int p = t + k * 1024;
        sv[k] = (p < NPRED) ? ms[p] : -1.0f;
    }

    for (int i = t; i < NBINS2; i += 1024) hh[i] = 0;
    if (t == 0) { lcnt = 0; ovf = 0; sB = 0; }
    __syncthreads();

    // pass A: fine per-batch histogram of score bits (LDS atomics, from regs)
#pragma unroll
    for (int k = 0; k < 25; ++k) {
        float s = sv[k];
        if (s > CONF_T) {
            unsigned bits = __float_as_uint(s);
            int bin = (int)(bits >> 11) - 0x7D000;
            bin = bin < 0 ? 0 : (bin > 8191 ? 8191 : bin);
            atomicAdd(&hh[bin], 1u);
        }
    }
    __syncthreads();

    // coarse sums: ctmp[t] = sum of fine bins [8t, 8t+8) (vectorized reads)
    unsigned* ctmp = (unsigned*)uni;   // 1024 u32 (keys region is free here)
    {
        const uint4* h4 = (const uint4*)hh;
        uint4 a = h4[t * 2], d = h4[t * 2 + 1];
        ctmp[t] = a.x + a.y + a.z + a.w + d.x + d.y + d.z + d.w;
    }
    __syncthreads();

    if (t < 64) {  // wave 0: two-level suffix search for boundary fine-bin B
        const int lane = t;
        const int hi = 1023 - 16 * lane;        // lane chunk: coarse [hi-15, hi]
        unsigned lc[16];
        unsigned sum = 0;
#pragma unroll
        for (int k = 0; k < 16; ++k) { lc[k] = ctmp[hi - k]; sum += lc[k]; }
        unsigned v = sum;
        for (int d = 1; d < 64; d <<= 1) {
            unsigned o = __shfl_up(v, d);
            if (lane >= d) v += o;
        }
        unsigned excl = v - sum;                // count strictly above my chunk
        u64 ball = __ballot(v >= NTOP);
        if (ball != 0) {
            int sel = __builtin_ctzll(ball);
            if (lane == sel) {
                unsigned run = excl, runBefore = 0;
                int C = 0;
                for (int k = 0; k < 16; ++k) {
                    runBefore = run;
                    run += lc[k];
                    if (run >= NTOP) { C = hi - k; break; }
                }
                const uint4* f4 = (const uint4*)&hh[C * 8];
                uint4 fa = f4[0], fb = f4[1];
                unsigned fbin[8] = {fa.x, fa.y, fa.z, fa.w, fb.x, fb.y, fb.z, fb.w};
                unsigned run2 = runBefore;
                int Bf = C * 8;
                for (int ff = 7; ff >= 0; --ff) {
                    run2 += fbin[ff];
                    if (run2 >= NTOP) { Bf = C * 8 + ff; break; }
                }
                sB = Bf;
            }
        }
    }
    __syncthreads();
    const int B = sB;

    // pass B: compact candidates (fine bin >= B) into LDS keys (from regs)
#pragma unroll
    for (int k = 0; k < 25; ++k) {
        float s = sv[k];
        if (s > CONF_T) {
            unsigned bits = __float_as_uint(s);
            int bin = (int)(bits >> 11) - 0x7D000;
            bin = bin < 0 ? 0 : (bin > 8191 ? 8191 : bin);
            if (bin >= B) {
                unsigned slot = atomicAdd(&lcnt, 1u);
                if (slot < CAP)
                    keys[slot] = ((u64)(~bits) << 32) | (unsigned)(t + k * 1024);
            }
        }
    }
    __syncthreads();
    unsigned c = lcnt; if (c > CAP) c = CAP;
    const bool fastSort = (c <= 1024u);
    const unsigned PAD = fastSort ? 1024u : (unsigned)CAP;
    for (unsigned i = c + t; i < PAD; i += 1024) keys[i] = ~0ULL;
    __syncthreads();

    if (fastSort) {
        // ---- 1024-element bitonic, 1 elem/thread ----
        u64 v = keys[t];
        for (unsigned k = 2; k <= 64; k <<= 1)
            for (unsigned j = k >> 1; j >= 1; j >>= 1) {
                u64 pv = shfl_xor_u64(v, (int)j);
                bool asc = (((unsigned)t & k) == 0u);
                bool lower = (((unsigned)t & j) == 0u);
                bool tm = (asc == lower);
                v = ((v < pv) == tm) ? v : pv;
            }
        for (unsigned k = 128; k <= 1024; k <<= 1) {
            for (unsigned j = k >> 1; j >= 64; j >>= 1) {
                keys[t] = v;
                __syncthreads();
                u64 pv = keys[(unsigned)t ^ j];
                bool asc = (((unsigned)t & k) == 0u);
                bool lower = (((unsigned)t & j) == 0u);
                bool tm = (asc == lower);
                v = ((v < pv) == tm) ? v : pv;
                __syncthreads();
            }
            for (unsigned j = 32; j >= 1; j >>= 1) {
                u64 pv = shfl_xor_u64(v, (int)j);
                bool asc = (((unsigned)t & k) == 0u);
                bool lower = (((unsigned)t & j) == 0u);
                bool tm = (asc == lower);
                v = ((v < pv) == tm) ? v : pv;
            }
        }
        keys[t] = v;
        __syncthreads();
    } else {
        // ---- fallback: 2048-element hybrid bitonic (round-5 verbatim) ----
        const unsigned ia = (((unsigned)t & ~63u) << 1) | ((unsigned)t & 63u);
        const unsigned ib = ia + 64u;
        auto ce = [&](u64& v, unsigned i, unsigned j, unsigned k) {
            u64 pv = shfl_xor_u64(v, (int)j);
            bool asc = ((i & k) == 0u);
            bool lower = ((i & j) == 0u);
            bool takeMin = (asc == lower);
            bool less = (v < pv);
            v = (takeMin == less) ? v : pv;
        };
        {
            u64 a = keys[ia], d = keys[ib];
            for (unsigned k = 2; k <= 64; k <<= 1)
                for (unsigned j = k >> 1; j >= 1; j >>= 1) {
                    ce(a, ia, j, k);
                    ce(d, ib, j, k);
                }
            keys[ia] = a; keys[ib] = d;
        }
        __syncthreads();
        for (unsigned k = 128; k <= CAP; k <<= 1) {
            for (unsigned j = k >> 1; j >= 64; j >>= 1) {
                unsigned i = (((unsigned)t & ~(j - 1)) << 1) | ((unsigned)t & (j - 1));
                unsigned pi = i | j;
                bool up = ((i & k) == 0);
                u64 a = keys[i], d = keys[pi];
                bool sw = up ? (a > d) : (a < d);
                if (sw) { keys[i] = d; keys[pi] = a; }
                __syncthreads();
            }
            u64 a = keys[ia], d = keys[ib];
            for (unsigned j = 32; j >= 1; j >>= 1) {
                ce(a, ia, j, k);
                ce(d, ib, j, k);
            }
            keys[ia] = a; keys[ib] = d;
            __syncthreads();
        }
    }

    // gather top-1000 into LDS SoA
    if (t < NTOP) {
        u64 key = keys[t];
        unsigned p = (unsigned)key;
        float score = __uint_as_float(~(unsigned)(key >> 32));
        bool v = score > CONF_T;
        float4 o = make_float4(0.f, 0.f, 0.f, 0.f);
        float co = 0.f; int cid = -1;
        if (v) {
            const float* xp = x + ((size_t)b * NPRED + p) * 85;
            float xc = xp[0], yc = xp[1], w = xp[2], h = xp[3];
            float hw = w * 0.5f, hh2 = h * 0.5f;
            o.x = xc - hw; o.y = yc - hh2; o.z = xc + hw; o.w = yc + hh2;
            cid = cls[(size_t)b * NPRED + p];
            co = (float)cid * MAXWH;
        }
        obx[t] = o; oco[t] = co; osc[t] = score; ocl[t] = cid;
    }
    __syncthreads();    // keys dead; overlay per-class rank bitmasks + sup

    u64* bm = (u64*)uni;                  // [80][16] u64 = 10240 B
    unsigned char* sup = uni + 10240;     // 1000 B
    for (int i = t; i < NCLS * 16; i += 1024) bm[i] = 0;
    if (t < NTOP) sup[t] = 0;
    __syncthreads();
    if (t < NTOP && ocl[t] >= 0)
        atomicOr(&bm[ocl[t] * 16 + (t >> 6)], 1ull << (t & 63));
    __syncthreads();

    // ---- per-class ballot greedy: one wave per class, lane = rank order ----
    {
        const int waveId = t >> 6, lane2 = t & 63;
        for (int c2 = waveId; c2 < NCLS; c2 += 16) {
            u64 w = (lane2 < 16) ? bm[c2 * 16 + lane2] : 0ull;
            int cum = 0, myw = -1, rem = 0;
            u64 myword = 0;
#pragma unroll
            for (int ww = 0; ww < 16; ++ww) {
                u64 wv = shfl_u64(w, ww);
                int pc = __popcll(wv);
                if (myw < 0 && lane2 < cum + pc) { myw = ww; rem = lane2 - cum; myword = wv; }
                cum += pc;
            }
            int n2 = cum;
            if (n2 == 0) continue;
            if (n2 > 64) { ovf = 1; continue; }   // benign race (all write 1)
            bool active = (lane2 < n2);
            int rank = 0;
            float ax1v = 0.f, ay1v = 0.f, ax2v = 0.f, ay2v = 0.f, arv = 0.f;
            if (active) {
                int pos = 0, r = rem;   // select rem-th set bit of myword
#pragma unroll
                for (int wd = 32; wd >= 1; wd >>= 1) {
                    u64 mask = ((1ull << wd) - 1ull) << pos;
                    int cc = __popcll(myword & mask);
                    if (r >= cc) { r -= cc; pos += wd; }
                }
                rank = myw * 64 + pos;
                float4 A = obx[rank]; float cA = oco[rank];
                ax1v = A.x + cA; ay1v = A.y + cA;
                ax2v = A.z + cA; ay2v = A.w + cA;
                arv = (ax2v - ax1v) * (ay2v - ay1v);
            }
            u64 alive = (n2 >= 64) ? ~0ull : ((1ull << n2) - 1ull);
            u64 kept = 0;
            while (alive) {
                int i = (int)__builtin_ctzll(alive);
                u64 bit = 1ull << i;
                kept |= bit;
                float bx1 = __shfl(ax1v, i), by1 = __shfl(ay1v, i);
                float bx2 = __shfl(ax2v, i), by2 = __shfl(ay2v, i);
                float bar = __shfl(arv, i);
                float ltx = fmaxf(bx1, ax1v), lty = fmaxf(by1, ay1v);
                float rbx = fminf(bx2, ax2v), rby = fminf(by2, ay2v);
                float ww2 = fmaxf(rbx - ltx, 0.0f), hh3 = fmaxf(rby - lty, 0.0f);
                float inter = ww2 * hh3;
                float iou = inter / (((bar + arv) - inter) + 1e-9f);
                u64 suppr = __ballot(iou > IOU_THR);
                alive &= ~(suppr | bit);
            }
            if (active) sup[rank] = ((kept >> lane2) & 1ull) ? 0 : 1;
        }
    }
    __syncthreads();

    // exact serial fallback for classes with >64 candidates (P ~ 1e-40)
    if (ovf && t == 0) {
        for (int c2 = 0; c2 < NCLS; ++c2) {
            int n2 = 0;
            for (int w2 = 0; w2 < 16; ++w2) n2 += __popcll(bm[c2 * 16 + w2]);
            if (n2 <= 64) continue;
            for (int a2 = 0; a2 < NTOP; ++a2) {
                if (ocl[a2] != c2 || sup[a2]) continue;
                float4 A = obx[a2]; float cA = oco[a2];
                float ax1 = A.x + cA, ay1 = A.y + cA;
                float ax2 = A.z + cA, ay2 = A.w + cA;
                float areaA = (ax2 - ax1) * (ay2 - ay1);
                for (int d2 = a2 + 1; d2 < NTOP; ++d2) {
                    if (ocl[d2] != c2 || sup[d2]) continue;
                    float4 Bb = obx[d2];
                    float bx1 = Bb.x + cA, by1 = Bb.y + cA;
                    float bx2 = Bb.z + cA, by2 = Bb.w + cA;
                    float ltx = fmaxf(ax1, bx1), lty = fmaxf(ay1, by1);
                    float rbx = fminf(ax2, bx2), rby = fminf(ay2, by2);
                    float ww = fmaxf(rbx - ltx, 0.0f), hh3 = fmaxf(rby - lty, 0.0f);
                    float inter = ww * hh3;
                    float areaB = (bx2 - bx1) * (by2 - by1);
                    float iou = inter / (((areaA + areaB) - inter) + 1e-9f);
                    if (iou > IOU_THR) sup[d2] = 1;
                }
            }
        }
    }
    __syncthreads();

    // masked output write
    if (t < NTOP) {
        bool keep = (ocl[t] >= 0) && (sup[t] == 0);
        float4 o = obx[t];
        size_t d6 = ((size_t)b * NTOP + t) * 6;
        out[d6 + 0] = keep ? o.x : 0.0f;
        out[d6 + 1] = keep ? o.y : 0.0f;
        out[d6 + 2] = keep ? o.z : 0.0f;
        out[d6 + 3] = keep ? o.w : 0.0f;
        out[d6 + 4] = keep ? osc[t] : 0.0f;
        out[d6 + 5] = keep ? (float)ocl[t] : 0.0f;
    }
}

// ---------------------------------------------------------------------------
extern "C" void kernel_launch(void* const* d_in, const int* in_sizes, int n_in,
                              void* d_out, int out_size, void* d_ws, size_t ws_size,
                              hipStream_t stream) {
    const float* x = (const float*)d_in[0];
    char* ws = (char*)d_ws;
    float* msc = (float*)(ws);                       //      0 .. 806400
    int* cls = (int*)(ws + 806400);                  // 806400 .. 1612800

    k_score<<<NB * SBPB, 256, 0, stream>>>(x, msc, cls);
    k_fused<<<NB, 1024, 0, stream>>>(x, msc, cls, (float*)d_out);
}